// Round 2
// baseline (1345.827 us; speedup 1.0000x reference)
//
#include <hip/hip_runtime.h>
#include <hip/hip_bf16.h>
#include <cstdint>

#define IN_CH 128
#define HC    64
#define ED    16
#define SLOPE 0.2f
#define BSH   6                 // 64 nodes per bucket
#define BNODES 64

// ---------------- Kernel 1: h = x@W, a_src, a_dst --------------------------
__global__ __launch_bounds__(256) void k_node(
    const float* __restrict__ x, const float* __restrict__ W,
    const float* __restrict__ att_src_p, const float* __restrict__ att_dst_p,
    float* __restrict__ h, float* __restrict__ a_src, float* __restrict__ a_dst,
    int N)
{
  int lane = threadIdx.x & 63;
  int gw = (blockIdx.x * blockDim.x + threadIdx.x) >> 6;
  int nwaves = (gridDim.x * blockDim.x) >> 6;
  float asv = att_src_p[lane];
  float adv = att_dst_p[lane];
  for (int n0 = gw * 4; n0 < N; n0 += nwaves * 4) {
    int n1 = min(n0 + 1, N - 1), n2 = min(n0 + 2, N - 1), n3 = min(n0 + 3, N - 1);
    const float4* xa = (const float4*)(x + (size_t)n0 * IN_CH);
    const float4* xb = (const float4*)(x + (size_t)n1 * IN_CH);
    const float4* xc = (const float4*)(x + (size_t)n2 * IN_CH);
    const float4* xd = (const float4*)(x + (size_t)n3 * IN_CH);
    float acc0 = 0.f, acc1 = 0.f, acc2 = 0.f, acc3 = 0.f;
#pragma unroll 4
    for (int k4 = 0; k4 < IN_CH / 4; k4++) {
      float4 va = xa[k4], vb = xb[k4], vc = xc[k4], vd = xd[k4];
      float w0 = W[(k4 * 4 + 0) * HC + lane];
      float w1 = W[(k4 * 4 + 1) * HC + lane];
      float w2 = W[(k4 * 4 + 2) * HC + lane];
      float w3 = W[(k4 * 4 + 3) * HC + lane];
      acc0 += va.x * w0 + va.y * w1 + va.z * w2 + va.w * w3;
      acc1 += vb.x * w0 + vb.y * w1 + vb.z * w2 + vb.w * w3;
      acc2 += vc.x * w0 + vc.y * w1 + vc.z * w2 + vc.w * w3;
      acc3 += vd.x * w0 + vd.y * w1 + vd.z * w2 + vd.w * w3;
    }
    h[(size_t)n0 * HC + lane] = acc0;
    if (n0 + 1 < N) h[(size_t)n1 * HC + lane] = acc1;
    if (n0 + 2 < N) h[(size_t)n2 * HC + lane] = acc2;
    if (n0 + 3 < N) h[(size_t)n3 * HC + lane] = acc3;
    float s0 = acc0 * asv, s1 = acc1 * asv, s2 = acc2 * asv, s3 = acc3 * asv;
    float d0 = acc0 * adv, d1 = acc1 * adv, d2 = acc2 * adv, d3 = acc3 * adv;
#pragma unroll
    for (int m = 1; m < 16; m <<= 1) {
      s0 += __shfl_xor(s0, m); s1 += __shfl_xor(s1, m);
      s2 += __shfl_xor(s2, m); s3 += __shfl_xor(s3, m);
      d0 += __shfl_xor(d0, m); d1 += __shfl_xor(d1, m);
      d2 += __shfl_xor(d2, m); d3 += __shfl_xor(d3, m);
    }
    if ((lane & 15) == 0) {
      int hh = lane >> 4;
      a_src[(size_t)n0 * 4 + hh] = s0; a_dst[(size_t)n0 * 4 + hh] = d0;
      if (n0 + 1 < N) { a_src[(size_t)n1 * 4 + hh] = s1; a_dst[(size_t)n1 * 4 + hh] = d1; }
      if (n0 + 2 < N) { a_src[(size_t)n2 * 4 + hh] = s2; a_dst[(size_t)n2 * 4 + hh] = d2; }
      if (n0 + 3 < N) { a_src[(size_t)n3 * 4 + hh] = s3; a_dst[(size_t)n3 * 4 + hh] = d3; }
    }
  }
}

// ---------------- Kernel 2: bucket histogram (LDS-aggregated) --------------
__global__ __launch_bounds__(256) void k_bhist(const int* __restrict__ dst, int E,
                                               int* __restrict__ bhist, int NBUCK)
{
  extern __shared__ int lh[];
  for (int i = threadIdx.x; i < NBUCK; i += 256) lh[i] = 0;
  __syncthreads();
  int stride = gridDim.x * 256;
  for (int e = blockIdx.x * 256 + threadIdx.x; e < E; e += stride)
    atomicAdd(&lh[dst[e] >> BSH], 1);
  __syncthreads();
  for (int i = threadIdx.x; i < NBUCK; i += 256) {
    int v = lh[i];
    if (v) atomicAdd(&bhist[i], v);
  }
}

// ---------------- Kernel 3: exclusive scan over buckets (single block) -----
__global__ __launch_bounds__(1024) void k_bscan(const int* __restrict__ bhist,
                                                int* __restrict__ brow, int NBUCK, int E)
{
  __shared__ int ts[1024];
  int t = threadIdx.x;
  int v = (t < NBUCK) ? bhist[t] : 0;
  ts[t] = v;
  __syncthreads();
  for (int off = 1; off < 1024; off <<= 1) {
    int u = (t >= off) ? ts[t - off] : 0;
    __syncthreads();
    ts[t] += u;
    __syncthreads();
  }
  if (t < NBUCK) brow[t] = ts[t] - v;
  if (t == 0) brow[NBUCK] = E;
}

// ---------------- Kernel 4: edge logits + exp + bucket scatter -------------
__global__ __launch_bounds__(256) void k_edge2(
    const int* __restrict__ ei, const float* __restrict__ ea,
    const float* __restrict__ W_edge, const float* __restrict__ att_edge,
    const float* __restrict__ a_src, const float* __restrict__ a_dst,
    const int* __restrict__ brow, int* __restrict__ bcur,
    uint32_t* __restrict__ pk, float* __restrict__ exv, int E)
{
  __shared__ float ve[ED * 4];
  if (threadIdx.x < 64) {
    int d = threadIdx.x >> 2, hh = threadIdx.x & 3;
    float s = 0.f;
#pragma unroll
    for (int c = 0; c < 16; c++) s += W_edge[d * HC + hh * 16 + c] * att_edge[hh * 16 + c];
    ve[d * 4 + hh] = s;
  }
  __syncthreads();
  int e = blockIdx.x * 256 + threadIdx.x;
  if (e >= E) return;
  int sn = ei[e], dn = ei[E + e];
  float4 as4 = *(const float4*)(a_src + (size_t)sn * 4);
  float4 ad4 = *(const float4*)(a_dst + (size_t)dn * 4);
  const float4* ea4 = (const float4*)(ea + (size_t)e * ED);
  float4 q0 = ea4[0], q1 = ea4[1], q2 = ea4[2], q3 = ea4[3];
  float eav[16] = {q0.x,q0.y,q0.z,q0.w, q1.x,q1.y,q1.z,q1.w,
                   q2.x,q2.y,q2.z,q2.w, q3.x,q3.y,q3.z,q3.w};
  float ae0 = 0.f, ae1 = 0.f, ae2 = 0.f, ae3 = 0.f;
#pragma unroll
  for (int d = 0; d < ED; d++) {
    float v = eav[d];
    ae0 += v * ve[d * 4 + 0]; ae1 += v * ve[d * 4 + 1];
    ae2 += v * ve[d * 4 + 2]; ae3 += v * ve[d * 4 + 3];
  }
  float al0 = as4.x + ad4.x + ae0;
  float al1 = as4.y + ad4.y + ae1;
  float al2 = as4.z + ad4.z + ae2;
  float al3 = as4.w + ad4.w + ae3;
  al0 = al0 > 0.f ? al0 : SLOPE * al0;
  al1 = al1 > 0.f ? al1 : SLOPE * al1;
  al2 = al2 > 0.f ? al2 : SLOPE * al2;
  al3 = al3 > 0.f ? al3 : SLOPE * al3;
  int b = dn >> BSH;
  int pos = brow[b] + atomicAdd(&bcur[b], 1);
  pk[pos] = ((uint32_t)sn << BSH) | (uint32_t)(dn & (BNODES - 1));
  *(float4*)(exv + (size_t)pos * 4) =
      make_float4(__expf(al0), __expf(al1), __expf(al2), __expf(al3));
}

// ---------------- Kernel 5: fused per-bucket aggregation in LDS ------------
__global__ __launch_bounds__(512) void k_agg2(
    const float* __restrict__ h,
    const float* __restrict__ a_src, const float* __restrict__ a_dst,
    const float* __restrict__ W_edge, const float* __restrict__ att_edge,
    const float* __restrict__ bias, const int* __restrict__ brow,
    const uint32_t* __restrict__ pk, const float* __restrict__ exv,
    float* __restrict__ out, int N)
{
  __shared__ float acc[BNODES * HC];     // 16 KB
  __shared__ float den[BNODES * 4];
  __shared__ float aes[4];
  int tid = threadIdx.x;
  for (int i = tid; i < BNODES * HC; i += 512) acc[i] = 0.f;
  for (int i = tid; i < BNODES * 4; i += 512) den[i] = 0.f;
  if (tid < 4) {
    float s = 0.f;
    for (int d = 0; d < ED; d++) {
      float vd = 0.f;
#pragma unroll
      for (int c = 0; c < 16; c++) vd += W_edge[d * HC + tid * 16 + c] * att_edge[tid * 16 + c];
      s += vd;
    }
    aes[tid] = s;
  }
  __syncthreads();
  int lane = tid & 63, wv = tid >> 6;    // 8 waves
  int hq = lane >> 4;
  int b = blockIdx.x;
  int s0 = brow[b], s1 = brow[b + 1];
  const int NW = 8;
  int p = s0 + wv;
  for (; p + 3 * NW < s1; p += 4 * NW) {
    int p0 = p, p1 = p + NW, p2 = p + 2 * NW, p3 = p + 3 * NW;
    uint32_t k0 = pk[p0], k1 = pk[p1], k2 = pk[p2], k3 = pk[p3];
    float e0 = exv[(size_t)p0 * 4 + hq];
    float e1 = exv[(size_t)p1 * 4 + hq];
    float e2 = exv[(size_t)p2 * 4 + hq];
    float e3 = exv[(size_t)p3 * 4 + hq];
    float h0 = h[(size_t)(k0 >> BSH) * HC + lane];
    float h1 = h[(size_t)(k1 >> BSH) * HC + lane];
    float h2 = h[(size_t)(k2 >> BSH) * HC + lane];
    float h3 = h[(size_t)(k3 >> BSH) * HC + lane];
    atomicAdd(&acc[(k0 & (BNODES - 1)) * HC + lane], h0 * e0);
    atomicAdd(&acc[(k1 & (BNODES - 1)) * HC + lane], h1 * e1);
    atomicAdd(&acc[(k2 & (BNODES - 1)) * HC + lane], h2 * e2);
    atomicAdd(&acc[(k3 & (BNODES - 1)) * HC + lane], h3 * e3);
    if ((lane & 15) == 0) {
      atomicAdd(&den[(k0 & (BNODES - 1)) * 4 + hq], e0);
      atomicAdd(&den[(k1 & (BNODES - 1)) * 4 + hq], e1);
      atomicAdd(&den[(k2 & (BNODES - 1)) * 4 + hq], e2);
      atomicAdd(&den[(k3 & (BNODES - 1)) * 4 + hq], e3);
    }
  }
  for (; p < s1; p += NW) {
    uint32_t k0 = pk[p];
    float e0 = exv[(size_t)p * 4 + hq];
    float h0 = h[(size_t)(k0 >> BSH) * HC + lane];
    atomicAdd(&acc[(k0 & (BNODES - 1)) * HC + lane], h0 * e0);
    if ((lane & 15) == 0) atomicAdd(&den[(k0 & (BNODES - 1)) * 4 + hq], e0);
  }
  __syncthreads();
  // finalize: wave wv handles nodes wv*8 .. wv*8+7 of this bucket
  int nb0 = b * BNODES;
  for (int j = wv * 8; j < wv * 8 + 8; j++) {
    int n = nb0 + j;
    if (n >= N) break;
    float asv = a_src[(size_t)n * 4 + hq];
    float adv = a_dst[(size_t)n * 4 + hq];
    float al = asv + adv + aes[hq];
    al = al > 0.f ? al : SLOPE * al;
    float exs = __expf(al);
    float num = acc[j * HC + lane] + exs * h[(size_t)n * HC + lane];
    float dd  = den[j * 4 + hq] + exs;
    out[(size_t)n * HC + lane] = num / dd + bias[lane];
  }
}

// ---------------- Launcher -------------------------------------------------
extern "C" void kernel_launch(void* const* d_in, const int* in_sizes, int n_in,
                              void* d_out, int out_size, void* d_ws, size_t ws_size,
                              hipStream_t stream)
{
  const float* x        = (const float*)d_in[0];
  const int*   ei       = (const int*)d_in[1];
  const float* ea       = (const float*)d_in[2];
  const float* W        = (const float*)d_in[3];
  const float* att_src  = (const float*)d_in[4];
  const float* att_dst  = (const float*)d_in[5];
  const float* W_edge   = (const float*)d_in[6];
  const float* att_edge = (const float*)d_in[7];
  const float* bias     = (const float*)d_in[8];
  float* out = (float*)d_out;

  int N = in_sizes[0] / IN_CH;
  int E = in_sizes[1] / 2;
  int NBUCK = (N + BNODES - 1) / BNODES;

  uint8_t* ws = (uint8_t*)d_ws;
  size_t off = 0;
  auto alloc = [&](size_t bytes) -> void* {
    void* p = ws + off;
    off = (off + bytes + 255) & ~(size_t)255;
    return p;
  };
  float* h        = (float*)alloc((size_t)N * HC * 4);
  float* a_src_w  = (float*)alloc((size_t)N * 4 * 4);
  float* a_dst_w  = (float*)alloc((size_t)N * 4 * 4);
  int*   bhist    = (int*)alloc((size_t)NBUCK * 2 * 4);  // hist + cursor, one memset
  int*   bcur     = bhist + NBUCK;
  int*   brow     = (int*)alloc(((size_t)NBUCK + 1) * 4);
  uint32_t* pk    = (uint32_t*)alloc((size_t)E * 4);
  float* exv      = (float*)alloc((size_t)E * 4 * 4);
  (void)ws_size; (void)n_in; (void)out_size;

  hipMemsetAsync(bhist, 0, (size_t)NBUCK * 2 * 4, stream);

  k_node<<<512, 256, 0, stream>>>(x, W, att_src, att_dst, h, a_src_w, a_dst_w, N);
  k_bhist<<<512, 256, NBUCK * 4, stream>>>(ei + E, E, bhist, NBUCK);
  k_bscan<<<1, 1024, 0, stream>>>(bhist, brow, NBUCK, E);
  k_edge2<<<(E + 255) / 256, 256, 0, stream>>>(ei, ea, W_edge, att_edge,
                                               a_src_w, a_dst_w, brow, bcur,
                                               pk, exv, E);
  k_agg2<<<NBUCK, 512, 0, stream>>>(h, a_src_w, a_dst_w, W_edge, att_edge,
                                    bias, brow, pk, exv, out, N);
}

// Round 3
// 506.161 us; speedup vs baseline: 2.6589x; 2.6589x over previous
//
#include <hip/hip_runtime.h>
#include <hip/hip_bf16.h>
#include <cstdint>

#define IN_CH 128
#define HC    64
#define ED    16
#define SLOPE 0.2f

// bf16 round-to-nearest-even pack/unpack
__device__ __forceinline__ uint32_t f2bf(float x) {
  uint32_t b = __float_as_uint(x);
  return (b + 0x7fffu + ((b >> 16) & 1u)) >> 16;
}
__device__ __forceinline__ float bf2f(uint32_t h) {
  return __uint_as_float(h << 16);
}

// ---------------- Kernel 1: h = x@W, a_src, a_dst --------------------------
__global__ __launch_bounds__(256) void k_node(
    const float* __restrict__ x, const float* __restrict__ W,
    const float* __restrict__ att_src_p, const float* __restrict__ att_dst_p,
    float* __restrict__ h, float* __restrict__ a_src, float* __restrict__ a_dst,
    int N)
{
  int lane = threadIdx.x & 63;
  int gw = (blockIdx.x * blockDim.x + threadIdx.x) >> 6;
  int nwaves = (gridDim.x * blockDim.x) >> 6;
  float asv = att_src_p[lane];
  float adv = att_dst_p[lane];
  for (int n0 = gw * 4; n0 < N; n0 += nwaves * 4) {
    int n1 = min(n0 + 1, N - 1), n2 = min(n0 + 2, N - 1), n3 = min(n0 + 3, N - 1);
    const float4* xa = (const float4*)(x + (size_t)n0 * IN_CH);
    const float4* xb = (const float4*)(x + (size_t)n1 * IN_CH);
    const float4* xc = (const float4*)(x + (size_t)n2 * IN_CH);
    const float4* xd = (const float4*)(x + (size_t)n3 * IN_CH);
    float acc0 = 0.f, acc1 = 0.f, acc2 = 0.f, acc3 = 0.f;
#pragma unroll 4
    for (int k4 = 0; k4 < IN_CH / 4; k4++) {
      float4 va = xa[k4], vb = xb[k4], vc = xc[k4], vd = xd[k4];
      float w0 = W[(k4 * 4 + 0) * HC + lane];
      float w1 = W[(k4 * 4 + 1) * HC + lane];
      float w2 = W[(k4 * 4 + 2) * HC + lane];
      float w3 = W[(k4 * 4 + 3) * HC + lane];
      acc0 += va.x * w0 + va.y * w1 + va.z * w2 + va.w * w3;
      acc1 += vb.x * w0 + vb.y * w1 + vb.z * w2 + vb.w * w3;
      acc2 += vc.x * w0 + vc.y * w1 + vc.z * w2 + vc.w * w3;
      acc3 += vd.x * w0 + vd.y * w1 + vd.z * w2 + vd.w * w3;
    }
    h[(size_t)n0 * HC + lane] = acc0;
    if (n0 + 1 < N) h[(size_t)n1 * HC + lane] = acc1;
    if (n0 + 2 < N) h[(size_t)n2 * HC + lane] = acc2;
    if (n0 + 3 < N) h[(size_t)n3 * HC + lane] = acc3;
    float s0 = acc0 * asv, s1 = acc1 * asv, s2 = acc2 * asv, s3 = acc3 * asv;
    float d0 = acc0 * adv, d1 = acc1 * adv, d2 = acc2 * adv, d3 = acc3 * adv;
#pragma unroll
    for (int m = 1; m < 16; m <<= 1) {
      s0 += __shfl_xor(s0, m); s1 += __shfl_xor(s1, m);
      s2 += __shfl_xor(s2, m); s3 += __shfl_xor(s3, m);
      d0 += __shfl_xor(d0, m); d1 += __shfl_xor(d1, m);
      d2 += __shfl_xor(d2, m); d3 += __shfl_xor(d3, m);
    }
    if ((lane & 15) == 0) {
      int hh = lane >> 4;
      a_src[(size_t)n0 * 4 + hh] = s0; a_dst[(size_t)n0 * 4 + hh] = d0;
      if (n0 + 1 < N) { a_src[(size_t)n1 * 4 + hh] = s1; a_dst[(size_t)n1 * 4 + hh] = d1; }
      if (n0 + 2 < N) { a_src[(size_t)n2 * 4 + hh] = s2; a_dst[(size_t)n2 * 4 + hh] = d2; }
      if (n0 + 3 < N) { a_src[(size_t)n3 * 4 + hh] = s3; a_dst[(size_t)n3 * 4 + hh] = d3; }
    }
  }
}

// ---------------- Kernel 2: degree histogram over dst ----------------------
__global__ __launch_bounds__(256) void k_hist(const int* __restrict__ dst, int E,
                                              int* __restrict__ deg)
{
  int e = blockIdx.x * 256 + threadIdx.x;
  if (e < E) atomicAdd(&deg[dst[e]], 1);
}

// ---------------- Kernel 3a/3b/3c: exclusive scan -> rowptr ----------------
__global__ __launch_bounds__(256) void k_scan_a(const int* __restrict__ deg, int N,
                                                int* __restrict__ rowptr,
                                                int* __restrict__ blksums)
{
  __shared__ int tsum[256];
  int tid = threadIdx.x;
  int base = blockIdx.x * 2048 + tid * 8;
  int pre[8];
  int s = 0;
#pragma unroll
  for (int j = 0; j < 8; j++) {
    int idx = base + j;
    int v = (idx < N) ? deg[idx] : 0;
    pre[j] = s; s += v;
  }
  tsum[tid] = s;
  __syncthreads();
  for (int offm = 1; offm < 256; offm <<= 1) {
    int t = (tid >= offm) ? tsum[tid - offm] : 0;
    __syncthreads();
    tsum[tid] += t;
    __syncthreads();
  }
  int excl = tsum[tid] - s;
#pragma unroll
  for (int j = 0; j < 8; j++) {
    int idx = base + j;
    if (idx < N) rowptr[idx] = excl + pre[j];
  }
  if (tid == 255) blksums[blockIdx.x] = tsum[255];
}

__global__ void k_scan_b(int* __restrict__ blksums, int NB)
{
  if (threadIdx.x == 0 && blockIdx.x == 0) {
    int run = 0;
    for (int b = 0; b < NB; b++) { int t = blksums[b]; blksums[b] = run; run += t; }
  }
}

__global__ __launch_bounds__(256) void k_scan_c(int* __restrict__ rowptr,
                                                const int* __restrict__ blksums,
                                                int N, int E)
{
  int i = blockIdx.x * 256 + threadIdx.x;
  if (i < N) rowptr[i] += blksums[i >> 11];
  if (i == 0) rowptr[N] = E;
}

// ---------------- Kernel 4: edge logits + exp + packed 16B CSR scatter -----
__global__ __launch_bounds__(256) void k_edge3(
    const int* __restrict__ ei, const float* __restrict__ ea,
    const float* __restrict__ W_edge, const float* __restrict__ att_edge,
    const float* __restrict__ a_src, const float* __restrict__ a_dst,
    const int* __restrict__ rowptr, int* __restrict__ cursor,
    uint4* __restrict__ pay, int E)
{
  __shared__ float ve[ED * 4];
  if (threadIdx.x < 64) {
    int d = threadIdx.x >> 2, hh = threadIdx.x & 3;
    float s = 0.f;
#pragma unroll
    for (int c = 0; c < 16; c++) s += W_edge[d * HC + hh * 16 + c] * att_edge[hh * 16 + c];
    ve[d * 4 + hh] = s;
  }
  __syncthreads();
  int e = blockIdx.x * 256 + threadIdx.x;
  if (e >= E) return;
  int sn = ei[e], dn = ei[E + e];
  float4 as4 = *(const float4*)(a_src + (size_t)sn * 4);
  float4 ad4 = *(const float4*)(a_dst + (size_t)dn * 4);
  const float4* ea4 = (const float4*)(ea + (size_t)e * ED);
  float4 q0 = ea4[0], q1 = ea4[1], q2 = ea4[2], q3 = ea4[3];
  float eav[16] = {q0.x,q0.y,q0.z,q0.w, q1.x,q1.y,q1.z,q1.w,
                   q2.x,q2.y,q2.z,q2.w, q3.x,q3.y,q3.z,q3.w};
  float ae0 = 0.f, ae1 = 0.f, ae2 = 0.f, ae3 = 0.f;
#pragma unroll
  for (int d = 0; d < ED; d++) {
    float v = eav[d];
    ae0 += v * ve[d * 4 + 0]; ae1 += v * ve[d * 4 + 1];
    ae2 += v * ve[d * 4 + 2]; ae3 += v * ve[d * 4 + 3];
  }
  float al0 = as4.x + ad4.x + ae0;
  float al1 = as4.y + ad4.y + ae1;
  float al2 = as4.z + ad4.z + ae2;
  float al3 = as4.w + ad4.w + ae3;
  al0 = al0 > 0.f ? al0 : SLOPE * al0;
  al1 = al1 > 0.f ? al1 : SLOPE * al1;
  al2 = al2 > 0.f ? al2 : SLOPE * al2;
  al3 = al3 > 0.f ? al3 : SLOPE * al3;
  int pos = rowptr[dn] + atomicAdd(&cursor[dn], 1);
  uint4 r;
  r.x = (uint32_t)sn;
  r.y = f2bf(__expf(al0)) | (f2bf(__expf(al1)) << 16);
  r.z = f2bf(__expf(al2)) | (f2bf(__expf(al3)) << 16);
  r.w = 0u;
  pay[pos] = r;
}

// ---------------- Kernel 5: per-node pull aggregation (4-deep ILP) ---------
__global__ __launch_bounds__(256) void k_agg3(
    const float* __restrict__ h,
    const float* __restrict__ a_src, const float* __restrict__ a_dst,
    const float* __restrict__ W_edge, const float* __restrict__ att_edge,
    const float* __restrict__ bias, const int* __restrict__ rowptr,
    const uint4* __restrict__ pay, float* __restrict__ out, int N)
{
  __shared__ float aes[4];
  if (threadIdx.x < 4) {
    int hh = threadIdx.x;
    float s = 0.f;
    for (int d = 0; d < ED; d++) {
      float vd = 0.f;
#pragma unroll
      for (int c = 0; c < 16; c++) vd += W_edge[d * HC + hh * 16 + c] * att_edge[hh * 16 + c];
      s += vd;
    }
    aes[hh] = s;
  }
  __syncthreads();
  int lane = threadIdx.x & 63;
  int n = blockIdx.x * 4 + (threadIdx.x >> 6);
  if (n >= N) return;
  int hq = lane >> 4;
  int b = rowptr[n], e = rowptr[n + 1];
  float acc = 0.f, den = 0.f;
  int p = b;
  for (; p + 3 < e; p += 4) {
    uint4 r0 = pay[p], r1 = pay[p + 1], r2 = pay[p + 2], r3 = pay[p + 3];
    uint32_t w0 = (hq & 2) ? r0.z : r0.y;
    uint32_t w1 = (hq & 2) ? r1.z : r1.y;
    uint32_t w2 = (hq & 2) ? r2.z : r2.y;
    uint32_t w3 = (hq & 2) ? r3.z : r3.y;
    float e0 = bf2f((hq & 1) ? (w0 >> 16) : (w0 & 0xffffu));
    float e1 = bf2f((hq & 1) ? (w1 >> 16) : (w1 & 0xffffu));
    float e2 = bf2f((hq & 1) ? (w2 >> 16) : (w2 & 0xffffu));
    float e3 = bf2f((hq & 1) ? (w3 >> 16) : (w3 & 0xffffu));
    float h0 = h[(size_t)r0.x * HC + lane];
    float h1 = h[(size_t)r1.x * HC + lane];
    float h2 = h[(size_t)r2.x * HC + lane];
    float h3 = h[(size_t)r3.x * HC + lane];
    acc += e0 * h0 + e1 * h1 + e2 * h2 + e3 * h3;
    den += (e0 + e1) + (e2 + e3);
  }
  for (; p < e; p++) {
    uint4 r0 = pay[p];
    uint32_t w0 = (hq & 2) ? r0.z : r0.y;
    float e0 = bf2f((hq & 1) ? (w0 >> 16) : (w0 & 0xffffu));
    acc += e0 * h[(size_t)r0.x * HC + lane];
    den += e0;
  }
  // self loop (edge_attr filled with 1.0)
  float al = a_src[(size_t)n * 4 + hq] + a_dst[(size_t)n * 4 + hq] + aes[hq];
  al = al > 0.f ? al : SLOPE * al;
  float exs = __expf(al);
  acc += exs * h[(size_t)n * HC + lane];
  den += exs;
  out[(size_t)n * HC + lane] = acc / den + bias[lane];
}

// ---------------- Launcher -------------------------------------------------
extern "C" void kernel_launch(void* const* d_in, const int* in_sizes, int n_in,
                              void* d_out, int out_size, void* d_ws, size_t ws_size,
                              hipStream_t stream)
{
  const float* x        = (const float*)d_in[0];
  const int*   ei       = (const int*)d_in[1];
  const float* ea       = (const float*)d_in[2];
  const float* W        = (const float*)d_in[3];
  const float* att_src  = (const float*)d_in[4];
  const float* att_dst  = (const float*)d_in[5];
  const float* W_edge   = (const float*)d_in[6];
  const float* att_edge = (const float*)d_in[7];
  const float* bias     = (const float*)d_in[8];
  float* out = (float*)d_out;

  int N = in_sizes[0] / IN_CH;
  int E = in_sizes[1] / 2;

  uint8_t* ws = (uint8_t*)d_ws;
  size_t off = 0;
  auto alloc = [&](size_t bytes) -> void* {
    void* p = ws + off;
    off = (off + bytes + 255) & ~(size_t)255;
    return p;
  };
  float* h        = (float*)alloc((size_t)N * HC * 4);
  float* a_src_w  = (float*)alloc((size_t)N * 4 * 4);
  float* a_dst_w  = (float*)alloc((size_t)N * 4 * 4);
  int*   deg      = (int*)alloc((size_t)N * 2 * 4);   // deg then cursor, one memset
  int*   cursor   = deg + N;
  int*   rowptr   = (int*)alloc(((size_t)N + 1) * 4);
  int*   blksums  = (int*)alloc(64 * 4);
  uint4* pay      = (uint4*)alloc((size_t)E * 16);
  (void)ws_size; (void)n_in; (void)out_size;

  hipMemsetAsync(deg, 0, (size_t)N * 2 * 4, stream);

  k_node<<<512, 256, 0, stream>>>(x, W, att_src, att_dst, h, a_src_w, a_dst_w, N);
  k_hist<<<(E + 255) / 256, 256, 0, stream>>>(ei + E, E, deg);
  int NB = (N + 2047) / 2048;
  k_scan_a<<<NB, 256, 0, stream>>>(deg, N, rowptr, blksums);
  k_scan_b<<<1, 64, 0, stream>>>(blksums, NB);
  k_scan_c<<<(N + 255) / 256, 256, 0, stream>>>(rowptr, blksums, N, E);
  k_edge3<<<(E + 255) / 256, 256, 0, stream>>>(ei, ea, W_edge, att_edge,
                                               a_src_w, a_dst_w, rowptr, cursor,
                                               pay, E);
  k_agg3<<<(N + 3) / 4, 256, 0, stream>>>(h, a_src_w, a_dst_w, W_edge, att_edge,
                                          bias, rowptr, pay, out, N);
}